// Round 1
// baseline (8293.091 us; speedup 1.0000x reference)
//
#include <hip/hip_runtime.h>
#include <hip/hip_bf16.h>

#define TT 512
#define BB 64
#define HH 128
#define GG 512   // 4*H

__device__ __forceinline__ float bflo(unsigned u) { return __uint_as_float(u << 16); }
__device__ __forceinline__ float bfhi(unsigned u) { return __uint_as_float(u & 0xffff0000u); }
__device__ __forceinline__ float ldf(const void* p, size_t i, int isbf) {
  return isbf ? __uint_as_float(((unsigned)((const unsigned short*)p)[i]) << 16)
              : ((const float*)p)[i];
}

// Detect whether float tensors are bf16 (flag=1) or f32 (flag=0), by checking
// whether the low 16 bits of emb's words look like bf16 values of N(0,1).
__global__ __launch_bounds__(256) void k_detect(const unsigned* __restrict__ bits,
                                                unsigned* __restrict__ flag) {
  __shared__ int cnt;
  if (threadIdx.x == 0) cnt = 0;
  __syncthreads();
  int local = 0;
  for (int i = threadIdx.x; i < 1024; i += 256) {
    unsigned e = (bits[i] >> 7) & 0xff;   // exponent field of low-half-as-bf16
    if (e >= 118 && e <= 134) local++;
  }
  atomicAdd(&cnt, local);
  __syncthreads();
  if (threadIdx.x == 0) *flag = (cnt > 768) ? 1u : 0u;
}

__global__ __launch_bounds__(256) void k_embed(const int* __restrict__ idx,
                                               const void* __restrict__ emb,
                                               const unsigned* __restrict__ flag,
                                               float* __restrict__ x0) {
  int isbf = (int)*flag;
  int i = blockIdx.x * 256 + threadIdx.x;     // over T*B*H
  int h = i & (HH - 1);
  int tb = i >> 7;
  x0[i] = ldf(emb, (size_t)idx[tb] * HH + h, isbf);
}

// C[M,512] = A[M,K] @ W[512,K]^T + bias ; M=32768 fixed by grid (512x8), tile 64x64
__global__ __launch_bounds__(256) void k_proj(const float* __restrict__ A,
                                              const void* __restrict__ W, size_t w_off,
                                              const void* __restrict__ bias, size_t b_off,
                                              float* __restrict__ C, int K,
                                              const unsigned* __restrict__ flag) {
  int isbf = (int)*flag;
  __shared__ float As[16][68];
  __shared__ float Bs[16][68];
  int tid = threadIdx.x;
  int tx = tid & 15, ty = tid >> 4;
  int m_base = blockIdx.x * 64, n_base = blockIdx.y * 64;
  float acc[4][4] = {};
  int kk = tid & 15, rr = tid >> 4;
  for (int k0 = 0; k0 < K; k0 += 16) {
    #pragma unroll
    for (int r = 0; r < 4; r++) {
      As[kk][rr + 16*r] = A[(size_t)(m_base + rr + 16*r) * K + k0 + kk];
      Bs[kk][rr + 16*r] = ldf(W, w_off + (size_t)(n_base + rr + 16*r) * K + k0 + kk, isbf);
    }
    __syncthreads();
    #pragma unroll
    for (int k = 0; k < 16; k++) {
      float4 av = *(const float4*)(&As[k][ty*4]);
      float4 bv = *(const float4*)(&Bs[k][tx*4]);
      float a[4] = {av.x, av.y, av.z, av.w};
      float b[4] = {bv.x, bv.y, bv.z, bv.w};
      #pragma unroll
      for (int i = 0; i < 4; i++)
        #pragma unroll
        for (int j = 0; j < 4; j++)
          acc[i][j] += a[i] * b[j];
    }
    __syncthreads();
  }
  #pragma unroll
  for (int i = 0; i < 4; i++) {
    #pragma unroll
    for (int j = 0; j < 4; j++) {
      int n = n_base + tx*4 + j;
      C[(size_t)(m_base + ty*4 + i) * GG + n] = acc[i][j] + ldf(bias, b_off + n, isbf);
    }
  }
}

// One block per batch element; 512 threads = one gate row each, W_hh row in registers.
__global__ __launch_bounds__(512, 2) void k_recur(const float* __restrict__ xg,
                                                  const void* __restrict__ whh, size_t w_off,
                                                  float* __restrict__ hout,
                                                  float* __restrict__ cfin, int dir,
                                                  const unsigned* __restrict__ flag) {
  int isbf = (int)*flag;
  __shared__ float h_lds[HH];
  __shared__ float g_lds[GG];
  int b = blockIdx.x;
  int j = threadIdx.x;
  float w[HH];
  if (isbf) {
    const uint4* wv = (const uint4*)whh;
    size_t base = (w_off >> 3) + (size_t)j * (HH / 8);
    #pragma unroll
    for (int q = 0; q < HH / 8; q++) {
      uint4 u = wv[base + q];
      w[q*8+0] = bflo(u.x); w[q*8+1] = bfhi(u.x);
      w[q*8+2] = bflo(u.y); w[q*8+3] = bfhi(u.y);
      w[q*8+4] = bflo(u.z); w[q*8+5] = bfhi(u.z);
      w[q*8+6] = bflo(u.w); w[q*8+7] = bfhi(u.w);
    }
  } else {
    const float4* wv = (const float4*)whh;
    size_t base = (w_off >> 2) + (size_t)j * (HH / 4);
    #pragma unroll
    for (int q = 0; q < HH / 4; q++) {
      float4 f = wv[base + q];
      w[q*4+0] = f.x; w[q*4+1] = f.y; w[q*4+2] = f.z; w[q*4+3] = f.w;
    }
  }
  float c = 0.f;
  if (j < HH) h_lds[j] = 0.f;
  __syncthreads();
  #pragma unroll 1
  for (int s = 0; s < TT; s++) {
    int t = (dir > 0) ? s : (TT - 1 - s);
    float g = xg[((size_t)t * BB + b) * GG + j];
    #pragma unroll
    for (int k4 = 0; k4 < HH / 4; k4++) {
      float4 hv = *(const float4*)(&h_lds[k4 * 4]);
      g += w[k4*4+0]*hv.x + w[k4*4+1]*hv.y + w[k4*4+2]*hv.z + w[k4*4+3]*hv.w;
    }
    g_lds[j] = g;
    __syncthreads();
    if (j < HH) {
      float gi = g_lds[j], gf = g_lds[HH + j], gc = g_lds[2*HH + j], go = g_lds[3*HH + j];
      float si = 1.f / (1.f + __expf(-gi));
      float sf = 1.f / (1.f + __expf(-gf));
      float so = 1.f / (1.f + __expf(-go));
      c = sf * c + si * tanhf(gc);
      float h = so * tanhf(c);
      h_lds[j] = h;
      hout[((size_t)t * BB + b) * HH + j] = h;
    }
    __syncthreads();
  }
  if (j < HH) cfin[(size_t)b * HH + j] = c;
}

__global__ __launch_bounds__(256) void k_concat(const float* __restrict__ hf,
                                                const float* __restrict__ hb,
                                                float* __restrict__ xcat) {
  int i = blockIdx.x * 256 + threadIdx.x;  // over T*B*2H
  int j = i & 255;
  int tb = i >> 8;
  xcat[i] = (j < HH) ? hf[(size_t)tb * HH + j] : hb[(size_t)tb * HH + j - HH];
}

__global__ __launch_bounds__(256) void k_add(float* __restrict__ dst, const float* __restrict__ src) {
  int i = blockIdx.x * 256 + threadIdx.x;
  dst[i] += src[i];
}

__global__ __launch_bounds__(256) void k_out(const float* __restrict__ x,
                                             const float* __restrict__ hlast,
                                             const float* __restrict__ cfin,
                                             void* __restrict__ out,
                                             const unsigned* __restrict__ flag) {
  int isbf = (int)*flag;
  int i = blockIdx.x * 256 + threadIdx.x;  // over T*B*H + B*H + B*H
  float v;
  if (i < TT * BB * HH) v = x[i];
  else if (i < TT * BB * HH + BB * HH) v = hlast[(size_t)(TT - 1) * BB * HH + (i - TT * BB * HH)];
  else v = cfin[i - TT * BB * HH - BB * HH];
  if (isbf) ((__hip_bfloat16*)out)[i] = __float2bfloat16(v);
  else ((float*)out)[i] = v;
}

extern "C" void kernel_launch(void* const* d_in, const int* in_sizes, int n_in,
                              void* d_out, int out_size, void* d_ws, size_t ws_size,
                              hipStream_t stream) {
  const int* idx = (const int*)d_in[0];
  const void* emb   = d_in[1];
  const void* w_ih0 = d_in[2];
  const void* w_hh0 = d_in[3];
  const void* b0    = d_in[4];
  const void* w_ih1 = d_in[5];
  const void* w_hh1 = d_in[6];
  const void* b1    = d_in[7];
  const void* w_ihr = d_in[8];
  const void* w_hhr = d_in[9];
  const void* br    = d_in[10];

  float* ws   = (float*)d_ws;
  float* x0   = ws;               // 4,194,304 floats [T,B,H]
  float* hf   = ws + 4194304;     // 4,194,304
  float* hb   = ws + 8388608;     // 4,194,304
  float* xcat = ws + 12582912;    // 8,388,608 [T,B,2H]
  float* xg   = ws + 20971520;    // 16,777,216 [T,B,4H]
  float* cfin = ws + 37748736;    // 8,192
  unsigned* flag = (unsigned*)(ws + 37756928);

  k_detect<<<1, 256, 0, stream>>>((const unsigned*)emb, flag);
  k_embed<<<16384, 256, 0, stream>>>(idx, emb, flag, x0);

  dim3 pg(512, 8);  // M/64 x N/64
  // Layer 0 forward
  k_proj<<<pg, 256, 0, stream>>>(x0, w_ih0, 0, b0, 0, xg, HH, flag);
  k_recur<<<64, 512, 0, stream>>>(xg, w_hh0, 0, hf, cfin, +1, flag);
  // Layer 0 backward
  k_proj<<<pg, 256, 0, stream>>>(x0, w_ih0, (size_t)GG * HH, b0, GG, xg, HH, flag);
  k_recur<<<64, 512, 0, stream>>>(xg, w_hh0, (size_t)GG * HH, hb, cfin, -1, flag);
  k_concat<<<32768, 256, 0, stream>>>(hf, hb, xcat);
  // Layer 1 (K = 2H)
  k_proj<<<pg, 256, 0, stream>>>(xcat, w_ih1, 0, b1, 0, xg, 2 * HH, flag);
  float* xcur = x0;
  k_recur<<<64, 512, 0, stream>>>(xg, w_hh1, 0, xcur, cfin, +1, flag);
  float* xtmp = hf;
  // Residual layers 2..7
  for (int r = 0; r < 6; r++) {
    k_proj<<<pg, 256, 0, stream>>>(xcur, w_ihr, (size_t)r * GG * HH, br, (size_t)r * GG, xg, HH, flag);
    k_recur<<<64, 512, 0, stream>>>(xg, w_hhr, (size_t)r * GG * HH, xtmp, cfin, +1, flag);
    k_add<<<16384, 256, 0, stream>>>(xcur, xtmp);
  }
  k_out<<<16448, 256, 0, stream>>>(xcur, xtmp, cfin, d_out, flag);
}

// Round 2
// 3958.820 us; speedup vs baseline: 2.0948x; 2.0948x over previous
//
#include <hip/hip_runtime.h>
#include <hip/hip_bf16.h>

#define TT 512
#define BB 64
#define HH 128
#define GG 512   // 4*H
#define TBH (TT*BB*HH)
#define TBG (TT*BB*GG)
#define BH (BB*HH)

__device__ __forceinline__ float bflo(unsigned u) { return __uint_as_float(u << 16); }
__device__ __forceinline__ float bfhi(unsigned u) { return __uint_as_float(u & 0xffff0000u); }
__device__ __forceinline__ float ldf(const void* p, size_t i, int isbf) {
  return isbf ? __uint_as_float(((unsigned)((const unsigned short*)p)[i]) << 16)
              : ((const float*)p)[i];
}

template<int CTRL>
__device__ __forceinline__ float dpp_add(float v) {
  int r = __builtin_amdgcn_mov_dpp(__float_as_int(v), CTRL, 0xF, 0xF, true);
  return v + __int_as_float(r);
}

__device__ __forceinline__ float sigm(float x) {
  return __builtin_amdgcn_rcpf(1.f + __expf(-x));
}
__device__ __forceinline__ float tanh_f(float x) {
  return fmaf(2.f, __builtin_amdgcn_rcpf(1.f + __expf(-2.f * x)), -1.f);
}

__global__ __launch_bounds__(256) void k_detect(const unsigned* __restrict__ bits,
                                                unsigned* __restrict__ flag) {
  __shared__ int cnt;
  if (threadIdx.x == 0) cnt = 0;
  __syncthreads();
  int local = 0;
  for (int i = threadIdx.x; i < 1024; i += 256) {
    unsigned e = (bits[i] >> 7) & 0xff;
    if (e >= 118 && e <= 134) local++;
  }
  atomicAdd(&cnt, local);
  __syncthreads();
  if (threadIdx.x == 0) *flag = (cnt > 768) ? 1u : 0u;
}

__global__ __launch_bounds__(256) void k_embed(const int* __restrict__ idx,
                                               const void* __restrict__ emb,
                                               const unsigned* __restrict__ flag,
                                               float* __restrict__ x0) {
  int isbf = (int)*flag;
  int i = blockIdx.x * 256 + threadIdx.x;
  int h = i & (HH - 1);
  int tb = i >> 7;
  x0[i] = ldf(emb, (size_t)idx[tb] * HH + h, isbf);
}

// C[M,512] = A[M,K] @ W[512,K]^T + bias ; grid (M/64, 8)
__global__ __launch_bounds__(256) void k_proj(const float* __restrict__ A,
                                              const void* __restrict__ W, size_t w_off,
                                              const void* __restrict__ bias, size_t b_off,
                                              float* __restrict__ C, int K,
                                              const unsigned* __restrict__ flag) {
  int isbf = (int)*flag;
  __shared__ float As[16][68];
  __shared__ float Bs[16][68];
  int tid = threadIdx.x;
  int tx = tid & 15, ty = tid >> 4;
  int m_base = blockIdx.x * 64, n_base = blockIdx.y * 64;
  float acc[4][4] = {};
  int kk = tid & 15, rr = tid >> 4;
  for (int k0 = 0; k0 < K; k0 += 16) {
    #pragma unroll
    for (int r = 0; r < 4; r++) {
      As[kk][rr + 16*r] = A[(size_t)(m_base + rr + 16*r) * K + k0 + kk];
      Bs[kk][rr + 16*r] = ldf(W, w_off + (size_t)(n_base + rr + 16*r) * K + k0 + kk, isbf);
    }
    __syncthreads();
    #pragma unroll
    for (int k = 0; k < 16; k++) {
      float4 av = *(const float4*)(&As[k][ty*4]);
      float4 bv = *(const float4*)(&Bs[k][tx*4]);
      float a[4] = {av.x, av.y, av.z, av.w};
      float b[4] = {bv.x, bv.y, bv.z, bv.w};
      #pragma unroll
      for (int i = 0; i < 4; i++)
        #pragma unroll
        for (int j = 0; j < 4; j++)
          acc[i][j] += a[i] * b[j];
    }
    __syncthreads();
  }
  #pragma unroll
  for (int i = 0; i < 4; i++) {
    #pragma unroll
    for (int j = 0; j < 4; j++) {
      int n = n_base + tx*4 + j;
      C[(size_t)(m_base + ty*4 + i) * GG + n] = acc[i][j] + ldf(bias, b_off + n, isbf);
    }
  }
}

// One block per (batch, direction). 512 threads: t -> j=t>>2 (h column), q=t&3 (K quarter).
// Each thread computes all 4 gates of column j over its K-quarter; DPP quad butterflies
// complete the dots. Double-buffered h in LDS -> one barrier per step.
__global__ __launch_bounds__(512, 2) void k_recur(
    const float* __restrict__ xg, size_t xg_dstride,
    const void* __restrict__ whh, size_t w_off, size_t w_dstride,
    float* __restrict__ hout, int hout_stride, int hout_doff,
    const float* __restrict__ res,
    float* __restrict__ hfin, float* __restrict__ cfin,
    int bidir, const unsigned* __restrict__ flag) {
  int isbf = (int)*flag;
  int d = blockIdx.x >> 6;
  int b = blockIdx.x & 63;
  int dir = (bidir == 2 || (bidir == 1 && d)) ? -1 : 1;
  xg += (size_t)d * xg_dstride;
  size_t woff = w_off + (size_t)d * w_dstride;
  int hcol = hout_doff * d;

  int t0 = threadIdx.x;
  int j = t0 >> 2, q = t0 & 3;

  // Load W_hh fragment: rows j + g*128, cols q*32 .. q*32+31  (128 f32 regs)
  float w[4][32];
  size_t wbase = woff + (size_t)j * HH + q * 32;
  if (isbf) {
    const uint4* wp = (const uint4*)whh;
    #pragma unroll
    for (int g = 0; g < 4; g++) {
      size_t b8 = (wbase + (size_t)g * 128 * HH) >> 3;
      #pragma unroll
      for (int u = 0; u < 4; u++) {
        uint4 v = wp[b8 + u];
        w[g][u*8+0] = bflo(v.x); w[g][u*8+1] = bfhi(v.x);
        w[g][u*8+2] = bflo(v.y); w[g][u*8+3] = bfhi(v.y);
        w[g][u*8+4] = bflo(v.z); w[g][u*8+5] = bfhi(v.z);
        w[g][u*8+6] = bflo(v.w); w[g][u*8+7] = bfhi(v.w);
      }
    }
  } else {
    const float4* wp = (const float4*)whh;
    #pragma unroll
    for (int g = 0; g < 4; g++) {
      size_t b4 = (wbase + (size_t)g * 128 * HH) >> 2;
      #pragma unroll
      for (int u = 0; u < 8; u++) {
        float4 v = wp[b4 + u];
        w[g][u*4+0] = v.x; w[g][u*4+1] = v.y; w[g][u*4+2] = v.z; w[g][u*4+3] = v.w;
      }
    }
  }

  __shared__ float h_lds[2][HH];
  if (t0 < HH) h_lds[0][t0] = 0.f;
  float c = 0.f;

  // prefetch step 0
  {
    int t = (dir > 0) ? 0 : (TT - 1);
  }
  int tfirst = (dir > 0) ? 0 : (TT - 1);
  size_t rg0 = ((size_t)tfirst * BB + b) * GG;
  float xg_cur[4];
  #pragma unroll
  for (int g = 0; g < 4; g++) xg_cur[g] = xg[rg0 + g * HH + j];
  float res_cur = res ? res[((size_t)tfirst * BB + b) * HH + j] : 0.f;
  __syncthreads();

  const float* hc = h_lds[0];
  float* hn = h_lds[1];

  #pragma unroll 1
  for (int s = 0; s < TT; s++) {
    int t = (dir > 0) ? s : (TT - 1 - s);
    // prefetch next step's xg / residual (issued before the dot; latency hidden)
    float xg_nxt[4] = {0.f, 0.f, 0.f, 0.f};
    float res_nxt = 0.f;
    if (s + 1 < TT) {
      int tn = (dir > 0) ? (s + 1) : (TT - 2 - s);
      size_t rg = ((size_t)tn * BB + b) * GG;
      #pragma unroll
      for (int g = 0; g < 4; g++) xg_nxt[g] = xg[rg + g * HH + j];
      if (res) res_nxt = res[((size_t)tn * BB + b) * HH + j];
    }
    // quarter dot
    float p0 = 0.f, p1 = 0.f, p2 = 0.f, p3 = 0.f;
    const float4* hq = (const float4*)(hc + (q << 5));
    #pragma unroll
    for (int u = 0; u < 8; u++) {
      float4 hv = hq[u];
      p0 = fmaf(w[0][u*4+0], hv.x, p0); p0 = fmaf(w[0][u*4+1], hv.y, p0);
      p0 = fmaf(w[0][u*4+2], hv.z, p0); p0 = fmaf(w[0][u*4+3], hv.w, p0);
      p1 = fmaf(w[1][u*4+0], hv.x, p1); p1 = fmaf(w[1][u*4+1], hv.y, p1);
      p1 = fmaf(w[1][u*4+2], hv.z, p1); p1 = fmaf(w[1][u*4+3], hv.w, p1);
      p2 = fmaf(w[2][u*4+0], hv.x, p2); p2 = fmaf(w[2][u*4+1], hv.y, p2);
      p2 = fmaf(w[2][u*4+2], hv.z, p2); p2 = fmaf(w[2][u*4+3], hv.w, p2);
      p3 = fmaf(w[3][u*4+0], hv.x, p3); p3 = fmaf(w[3][u*4+1], hv.y, p3);
      p3 = fmaf(w[3][u*4+2], hv.z, p3); p3 = fmaf(w[3][u*4+3], hv.w, p3);
    }
    // quad butterfly (VALU DPP, not DS): lanes q=0..3 all end with full dots
    p0 = dpp_add<0xB1>(p0); p0 = dpp_add<0x4E>(p0);
    p1 = dpp_add<0xB1>(p1); p1 = dpp_add<0x4E>(p1);
    p2 = dpp_add<0xB1>(p2); p2 = dpp_add<0x4E>(p2);
    p3 = dpp_add<0xB1>(p3); p3 = dpp_add<0x4E>(p3);

    float gi = p0 + xg_cur[0], gf = p1 + xg_cur[1];
    float gc = p2 + xg_cur[2], go = p3 + xg_cur[3];
    float si = sigm(gi), sf = sigm(gf), so = sigm(go);
    c = fmaf(sf, c, si * tanh_f(gc));
    float h = so * tanh_f(c);

    if (q == 0) {
      hn[j] = h;
      hout[((size_t)t * BB + b) * hout_stride + hcol + j] = h + res_cur;
      if (t == TT - 1) hfin[(size_t)(d * BB + b) * HH + j] = h;
    }
    #pragma unroll
    for (int g = 0; g < 4; g++) xg_cur[g] = xg_nxt[g];
    res_cur = res_nxt;
    __syncthreads();
    const float* tmp = hc; hc = hn; hn = (float*)tmp;
  }
  if (q == 0) cfin[(size_t)(d * BB + b) * HH + j] = c;
}

__global__ __launch_bounds__(256) void k_out(const float* __restrict__ x,
                                             const float* __restrict__ hfin,
                                             const float* __restrict__ cfin,
                                             void* __restrict__ out,
                                             const unsigned* __restrict__ flag) {
  int isbf = (int)*flag;
  int i = blockIdx.x * 256 + threadIdx.x;
  float v;
  if (i < TBH) v = x[i];
  else if (i < TBH + BH) v = hfin[i - TBH];
  else v = cfin[i - TBH - BH];
  if (isbf) ((__hip_bfloat16*)out)[i] = __float2bfloat16(v);
  else ((float*)out)[i] = v;
}

extern "C" void kernel_launch(void* const* d_in, const int* in_sizes, int n_in,
                              void* d_out, int out_size, void* d_ws, size_t ws_size,
                              hipStream_t stream) {
  const int* idx = (const int*)d_in[0];
  const void* emb   = d_in[1];
  const void* w_ih0 = d_in[2];
  const void* w_hh0 = d_in[3];
  const void* b0    = d_in[4];
  const void* w_ih1 = d_in[5];
  const void* w_hh1 = d_in[6];
  const void* b1    = d_in[7];
  const void* w_ihr = d_in[8];
  const void* w_hhr = d_in[9];
  const void* br    = d_in[10];

  float* ws   = (float*)d_ws;
  float* x0   = ws;                       // TBH
  float* xcat = ws + TBH;                 // 2*TBH  (xA = xcat, xB = xcat+TBH after L1)
  float* xg_f = ws + 3 * (size_t)TBH;     // TBG
  float* hfin = ws + 3 * (size_t)TBH + TBG;        // 2*BH
  float* cfin = hfin + 2 * BH;                     // 2*BH
  unsigned* flag = (unsigned*)(cfin + 2 * BH);
  float* xg_b = cfin + 2 * BH + 16384;    // TBG (merged path only)
  int merged = ws_size >= (size_t)(3 * (size_t)TBH + 2 * (size_t)TBG + 4 * BH + 16384 + 64) * 4;

  k_detect<<<1, 256, 0, stream>>>((const unsigned*)emb, flag);
  k_embed<<<TBH / 256, 256, 0, stream>>>(idx, emb, flag, x0);

  dim3 pg(512, 8);
  if (merged) {
    // L0 fwd+bwd concurrent: 128 blocks
    k_proj<<<pg, 256, 0, stream>>>(x0, w_ih0, 0, b0, 0, xg_f, HH, flag);
    k_proj<<<pg, 256, 0, stream>>>(x0, w_ih0, (size_t)GG * HH, b0, GG, xg_b, HH, flag);
    k_recur<<<128, 512, 0, stream>>>(xg_f, (size_t)(xg_b - xg_f), w_hh0, 0, (size_t)GG * HH,
                                     xcat, 2 * HH, HH, nullptr, hfin, cfin, 1, flag);
  } else {
    k_proj<<<pg, 256, 0, stream>>>(x0, w_ih0, 0, b0, 0, xg_f, HH, flag);
    k_recur<<<64, 512, 0, stream>>>(xg_f, 0, w_hh0, 0, 0,
                                    xcat, 2 * HH, 0, nullptr, hfin, cfin, 0, flag);
    k_proj<<<pg, 256, 0, stream>>>(x0, w_ih0, (size_t)GG * HH, b0, GG, xg_f, HH, flag);
    k_recur<<<64, 512, 0, stream>>>(xg_f, 0, w_hh0, (size_t)GG * HH, 0,
                                    xcat + HH, 2 * HH, 0, nullptr, hfin, cfin, 2, flag);
  }
  // layer 1: reads xcat [T,B,2H], writes xA (= xcat region, safe: proj done before recur)
  float* xA = xcat;
  float* xB = xcat + TBH;
  k_proj<<<pg, 256, 0, stream>>>(xcat, w_ih1, 0, b1, 0, xg_f, 2 * HH, flag);
  k_recur<<<64, 512, 0, stream>>>(xg_f, 0, w_hh1, 0, 0, xA, HH, 0, nullptr, hfin, cfin, 0, flag);
  // residual layers 2..7
  float* cur = xA;
  float* nxt = xB;
  for (int r = 0; r < 6; r++) {
    k_proj<<<pg, 256, 0, stream>>>(cur, w_ihr, (size_t)r * GG * HH, br, (size_t)r * GG, xg_f, HH, flag);
    k_recur<<<64, 512, 0, stream>>>(xg_f, 0, w_hhr, (size_t)r * GG * HH, 0,
                                    nxt, HH, 0, cur, hfin, cfin, 0, flag);
    float* t = cur; cur = nxt; nxt = t;
  }
  k_out<<<(TBH + 2 * BH) / 256, 256, 0, stream>>>(cur, hfin, cfin, d_out, flag);
}